// Round 3
// baseline (76.399 us; speedup 1.0000x reference)
//
#include <hip/hip_runtime.h>

#define BB 2
#define NPTS 100
#define PP 1024
#define NN 1125
#define NPAD 1152
#define NSCALE 4
#define NG 16
#define KPAD 5
#define CAMTHR 0.2f

#define R 25                              // rows per i-chunk
#define IC 45                             // i-chunks (IC*R == NN)
#define JT 5                              // j-tiles of 256
#define PSTRIDE (BB * NG * NPAD)          // ic-stride in partial arrays
#define PSZ (IC * PSTRIDE)

#define N_ROWSUM (3 * BB * NN)
#define N_INITV (BB * NG)

// workspace layout (floats)
#define WS_ROWSUM 0                           // [3][BB][NPAD]  rs for blocks 8..10
#define WS_VS (3 * BB * NPAD)                 // [4][BB][NG][NPAD] materialized V3..V1
#define WS_P0 (WS_VS + 4 * BB * NG * NPAD)    // stage-10 partials (V2 pieces)
#define WS_P1 (WS_P0 + PSZ)                   // stage-9 partials (V1 pieces)
#define WS_P2 (WS_P1 + PSZ)                   // stage-8 partials (V0 pieces)

__device__ __forceinline__ float wave_sum(float s) {
#pragma unroll
    for (int m = 32; m > 0; m >>= 1) s += __shfl_xor(s, m, 64);
    return s;
}

// ---------------------------------------------------------------------------
// K1: wave-per-row. Tasks 0..6749: rowsums (+1) of aug blocks 8..10.
//     Tasks 6750..6781: initial vectors V3 = row r of normalized aug[11].
__global__ __launch_bounds__(256) void prep_kernel(const float* __restrict__ A,
                                                   const int* __restrict__ pos,
                                                   float* __restrict__ ws) {
    int wave = threadIdx.x >> 6;
    int lane = threadIdx.x & 63;
    int task = blockIdx.x * 4 + wave;
    if (task < N_ROWSUM) {
        int i = task % NN;
        int b = (task / NN) % BB;
        int kk = task / (NN * BB);
        const float* row = A + (((size_t)(8 + kk) * BB + b) * NN + i) * NN;
        float s = 0.f;
#pragma unroll
        for (int k = 0; k < 17; ++k) s += row[lane + 64 * k];
        if (lane < NN - 17 * 64) s += row[lane + 17 * 64];
        s = wave_sum(s);
        if (lane == 0) ws[WS_ROWSUM + (kk * BB + b) * NPAD + i] = s + 1.0f;
    } else if (task < N_ROWSUM + N_INITV) {
        int t = task - N_ROWSUM;
        int g = t % NG;
        int b = t / NG;
        int r = NN - NPTS + pos[b * NG + g];
        const float* row = A + (((size_t)11 * BB + b) * NN + r) * NN;
        float s = 0.f;
#pragma unroll
        for (int k = 0; k < 17; ++k) s += row[lane + 64 * k];
        if (lane < NN - 17 * 64) s += row[lane + 17 * 64];
        s = wave_sum(s);
        float inv = 1.0f / (s + 1.0f);
        float* v = ws + WS_VS + ((size_t)(3 * BB + b) * NG + g) * NPAD;
        for (int j = lane; j < NN; j += 64)
            v[j] = (row[j] + (j == r ? 1.0f : 0.0f)) * inv;
    }
}

// ---------------------------------------------------------------------------
// K2: one stage. Block (ic,b,jt):
//   1) builds its 25-row normalized weight window w[il][g] = V_in[i0+il]/rs[i0+il],
//      where V_in comes either from materialized vin (stage 10) or by reducing
//      the previous stage's partials (identical redundant work across jt -> idempotent);
//      optionally writes the materialized V_in for post.
//   2) computes partial[ic][g][j] = sum_il w*A[i0+il][j]  (+ w[j-i0] diagonal/identity).
__global__ __launch_bounds__(256) void stage_kernel(
        const float* __restrict__ A, const float* __restrict__ rsb,
        const float* __restrict__ vin, const float* __restrict__ prevP,
        float* __restrict__ curP, float* __restrict__ vout, int blk) {
    __shared__ float Wl[R * NG];          // [il][g]
    int x = blockIdx.x;
    int jt = x % JT;
    int b = (x / JT) % BB;
    int ic = x / (JT * BB);
    int i0 = ic * R;
    const float* rs = rsb + b * NPAD;
    for (int idx = threadIdx.x; idx < R * NG; idx += 256) {
        int il = idx >> 4;
        int g = idx & 15;
        size_t voff = (size_t)(b * NG + g) * NPAD + i0 + il;
        float v;
        if (prevP) {
            float s = 0.f;
            const float* pp = prevP + voff;
#pragma unroll
            for (int c = 0; c < IC; ++c) s += pp[(size_t)c * PSTRIDE];
            v = s;
            if (vout) vout[voff] = v;     // idempotent across jt blocks
        } else {
            v = vin[voff];
        }
        Wl[idx] = v / rs[i0 + il];
    }
    __syncthreads();
    int j = jt * 256 + threadIdx.x;
    if (j >= NN) return;
    float acc[NG];
#pragma unroll
    for (int g = 0; g < NG; ++g) acc[g] = 0.f;
    const float* Ab = A + (((size_t)blk * BB + b) * NN + i0) * NN + j;
#pragma unroll
    for (int il = 0; il < R; ++il) {
        float a = Ab[(size_t)il * NN];
#pragma unroll
        for (int g = 0; g < NG; ++g) acc[g] += Wl[il * NG + g] * a;
    }
    int d = j - i0;
    if (d >= 0 && d < R) {                // identity term lives in the diagonal chunk
#pragma unroll
        for (int g = 0; g < NG; ++g) acc[g] += Wl[d * NG + g];
    }
    float* po = curP + (size_t)(ic * BB + b) * NG * NPAD + j;
#pragma unroll
    for (int g = 0; g < NG; ++g) po[(size_t)g * NPAD] = acc[g];
}

// ---------------------------------------------------------------------------
// K3: per-image normalize, binarize, morph close (zero-pad), bbox.
//     s==0 images reduce V0 from the stage-8 partials themselves.
__global__ __launch_bounds__(1024) void post_kernel(const float* __restrict__ ws,
                                                    float* __restrict__ out) {
    __shared__ float redA[1024];
    __shared__ float redB[1024];
    __shared__ float img[1024];
    __shared__ float tmp[1024];
    int idx = blockIdx.x;                 // (b*NG+g)*NSCALE + s
    int s = idx % NSCALE;
    int g = (idx / NSCALE) % NG;
    int b = idx / (NSCALE * NG);
    int p = threadIdx.x;                  // 0..1023
    float cam;
    if (s == 0) {
        const float* pp = ws + WS_P2 + (size_t)(b * NG + g) * NPAD + 1 + p;
        float t = 0.f;
#pragma unroll
        for (int c = 0; c < IC; ++c) t += pp[(size_t)c * PSTRIDE];
        cam = t;
    } else {
        cam = ws[WS_VS + ((size_t)(s * BB + b) * NG + g) * NPAD + 1 + p];
    }
    redA[p] = cam;
    redB[p] = cam;
    __syncthreads();
    for (int st = 512; st > 0; st >>= 1) {
        if (p < st) {
            redA[p] = fminf(redA[p], redA[p + st]);
            redB[p] = fmaxf(redB[p], redB[p + st]);
        }
        __syncthreads();
    }
    float mn = redA[0], mx = redB[0];
    float camn = (cam - mn) / (mx - mn + 1e-6f);
    out[(size_t)idx * PP + p] = camn;
    float bin = camn >= CAMTHR ? 1.0f : 0.0f;
    __syncthreads();                      // done reading redA/redB
    img[p] = bin;
    __syncthreads();
    int y = p >> 5, x = p & 31;
    // dilate horizontal (pad-0 under max == clip)
    float m = 0.f;
    for (int dx = -KPAD; dx <= KPAD; ++dx) {
        int xx = x + dx;
        if (xx >= 0 && xx < 32) m = fmaxf(m, img[(y << 5) | xx]);
    }
    tmp[p] = m;
    __syncthreads();
    // dilate vertical
    m = 0.f;
    for (int dy = -KPAD; dy <= KPAD; ++dy) {
        int yy = y + dy;
        if (yy >= 0 && yy < 32) m = fmaxf(m, tmp[(yy << 5) | x]);
    }
    __syncthreads();
    img[p] = m;                           // dilated
    __syncthreads();
    // erode horizontal, zero-pad: border forced 0
    float e;
    if (x < KPAD || x > 31 - KPAD) {
        e = 0.f;
    } else {
        e = 1e30f;
        for (int dx = -KPAD; dx <= KPAD; ++dx) e = fminf(e, img[(y << 5) | (x + dx)]);
    }
    tmp[p] = e;
    __syncthreads();
    float ev;
    if (y < KPAD || y > 31 - KPAD) {
        ev = 0.f;
    } else {
        ev = 1e30f;
        for (int dy = -KPAD; dy <= KPAD; ++dy) ev = fminf(ev, tmp[((y + dy) << 5) | x]);
    }
    out[(size_t)(BB * NG * NSCALE) * PP + (size_t)idx * PP + p] = ev;
    bool fg = ev > 0.5f;
    // bbox via min/max reductions over all pixels
    redA[p] = fg ? (float)x : 1e9f;
    redB[p] = fg ? (float)x : -1e9f;
    __syncthreads();
    for (int st = 512; st > 0; st >>= 1) {
        if (p < st) {
            redA[p] = fminf(redA[p], redA[p + st]);
            redB[p] = fmaxf(redB[p], redB[p + st]);
        }
        __syncthreads();
    }
    float xmin = redA[0], xmax = redB[0];
    __syncthreads();
    redA[p] = fg ? (float)y : 1e9f;
    redB[p] = fg ? (float)y : -1e9f;
    __syncthreads();
    for (int st = 512; st > 0; st >>= 1) {
        if (p < st) {
            redA[p] = fminf(redA[p], redA[p + st]);
            redB[p] = fmaxf(redB[p], redB[p + st]);
        }
        __syncthreads();
    }
    if (p == 0) {
        float ymin = redA[0], ymax = redB[0];
        float* bb = out + (size_t)(BB * NG * NSCALE) * PP * 2 + (size_t)idx * 4;
        if (xmax < -1e8f) {
            bb[0] = 0.f; bb[1] = 0.f; bb[2] = 1.f; bb[3] = 1.f;
        } else {
            bb[0] = xmin; bb[1] = ymin; bb[2] = xmax; bb[3] = ymax;
        }
    }
}

extern "C" void kernel_launch(void* const* d_in, const int* in_sizes, int n_in,
                              void* d_out, int out_size, void* d_ws, size_t ws_size,
                              hipStream_t stream) {
    const float* A = (const float*)d_in[0];
    const int* pos = (const int*)d_in[1];
    float* out = (float*)d_out;
    float* ws = (float*)d_ws;

    const float* rs2 = ws + WS_ROWSUM + 2 * BB * NPAD;   // block 10
    const float* rs1 = ws + WS_ROWSUM + 1 * BB * NPAD;   // block 9
    const float* rs0 = ws + WS_ROWSUM + 0 * BB * NPAD;   // block 8
    float* VS3 = ws + WS_VS + 3 * BB * NG * NPAD;
    float* VS2 = ws + WS_VS + 2 * BB * NG * NPAD;
    float* VS1 = ws + WS_VS + 1 * BB * NG * NPAD;

    prep_kernel<<<(N_ROWSUM + N_INITV + 3) / 4, 256, 0, stream>>>(A, pos, ws);
    // stage 10: V3 -> partials of V2
    stage_kernel<<<IC * BB * JT, 256, 0, stream>>>(A, rs2, VS3, nullptr,
                                                   ws + WS_P0, nullptr, 10);
    // stage 9: reduce V2, materialize it, -> partials of V1
    stage_kernel<<<IC * BB * JT, 256, 0, stream>>>(A, rs1, nullptr, ws + WS_P0,
                                                   ws + WS_P1, VS2, 9);
    // stage 8: reduce V1, materialize it, -> partials of V0
    stage_kernel<<<IC * BB * JT, 256, 0, stream>>>(A, rs0, nullptr, ws + WS_P1,
                                                   ws + WS_P2, VS1, 8);
    post_kernel<<<BB * NG * NSCALE, 1024, 0, stream>>>(ws, out);
}